// Round 1
// 81.426 us; speedup vs baseline: 1.0474x; 1.0474x over previous
//
#include <hip/hip_runtime.h>

#define NA 7
#define BLK 256

// Constant buffer layout in ws (floats):
//  joint j in [0,7): off j*30 -> P[9](=F3_j), Q[9](=F3_j K_j), S[9](=F3_j K_j^2), t[3]
//  off 210: F3_7[9], t_7[3]   (222 floats total)
__global__ void prep_kernel(const float* __restrict__ ft,
                            const float* __restrict__ ax,
                            float* __restrict__ cst)
{
    const int j = threadIdx.x;
    if (j >= 8) return;
    const float* F = ft + j * 16;
    float F3[9] = {F[0], F[1], F[2], F[4], F[5], F[6], F[8], F[9], F[10]};
    float tv[3] = {F[3], F[7], F[11]};
    if (j < NA) {
        float x = ax[j * 3 + 0], y = ax[j * 3 + 1], z = ax[j * 3 + 2];
        float K[9] = {0.f, -z, y,  z, 0.f, -x,  -y, x, 0.f};
        float KK[9];
        #pragma unroll
        for (int a = 0; a < 3; ++a)
            #pragma unroll
            for (int c = 0; c < 3; ++c) {
                float s = 0.f;
                #pragma unroll
                for (int b = 0; b < 3; ++b) s += K[a * 3 + b] * K[b * 3 + c];
                KK[a * 3 + c] = s;
            }
        float* dst = cst + j * 30;
        #pragma unroll
        for (int i = 0; i < 9; ++i) dst[i] = F3[i];
        #pragma unroll
        for (int a = 0; a < 3; ++a)
            #pragma unroll
            for (int c = 0; c < 3; ++c) {
                float q = 0.f, s2 = 0.f;
                #pragma unroll
                for (int b = 0; b < 3; ++b) {
                    q  += F3[a * 3 + b] * K[b * 3 + c];
                    s2 += F3[a * 3 + b] * KK[b * 3 + c];
                }
                dst[9  + a * 3 + c] = q;
                dst[18 + a * 3 + c] = s2;
            }
        dst[27] = tv[0]; dst[28] = tv[1]; dst[29] = tv[2];
    } else {
        float* dst = cst + 210;
        #pragma unroll
        for (int i = 0; i < 9; ++i) dst[i] = F3[i];
        dst[9] = tv[0]; dst[10] = tv[1]; dst[11] = tv[2];
    }
}

__global__ __launch_bounds__(BLK) void fk_kernel(
    const float* __restrict__ jp,   // (B, 7)
    const float* __restrict__ cst,  // 222 floats, uniform -> s_load
    float* __restrict__ out)        // (B, 4, 4)
{
    // One 1024-float region per wave, reused for input staging then output
    // transpose. All exchange is wave-local: no __syncthreads anywhere.
    __shared__ __attribute__((aligned(16))) float buf[BLK * 16];

    const int t = threadIdx.x;
    const int l = t & 63;
    const int w = t >> 6;
    const long long waveItem = (long long)blockIdx.x * BLK + (w << 6);

    float* wbuf = buf + (w << 10);

    // ---- stage this wave's 448 joint angles (64 items x 7), float4-coalesced ----
    {
        const float4* g4 = (const float4*)(jp + waveItem * 7);  // 112 float4, 16B-aligned
        float4* s4 = (float4*)wbuf;
        s4[l] = g4[l];
        if (l < 48) s4[64 + l] = g4[64 + l];
    }
    asm volatile("s_waitcnt lgkmcnt(0)" ::: "memory");

    // ---- per-thread chain; constants come in through the scalar pipe ----
    float A[9], tr[3];
    {
        float s, c;
        __sincosf(wbuf[l * 7 + 0], &s, &c);
        const float oc = 1.0f - c;
        const float* d = cst;
        #pragma unroll
        for (int i = 0; i < 9; ++i) A[i] = d[i] + s * d[9 + i] + oc * d[18 + i];
        tr[0] = d[27]; tr[1] = d[28]; tr[2] = d[29];
    }
    #pragma unroll
    for (int j = 1; j < NA; ++j) {
        const float* d = cst + j * 30;
        float s, c;
        __sincosf(wbuf[l * 7 + j], &s, &c);
        const float oc = 1.0f - c;
        float m[9];
        #pragma unroll
        for (int i = 0; i < 9; ++i) m[i] = d[i] + s * d[9 + i] + oc * d[18 + i];
        // tr = A @ t_j + tr   (uses old A)
        float t0 = tr[0] + A[0] * d[27] + A[1] * d[28] + A[2] * d[29];
        float t1 = tr[1] + A[3] * d[27] + A[4] * d[28] + A[5] * d[29];
        float t2 = tr[2] + A[6] * d[27] + A[7] * d[28] + A[8] * d[29];
        tr[0] = t0; tr[1] = t1; tr[2] = t2;
        // A = A @ m
        float N[9];
        #pragma unroll
        for (int a = 0; a < 3; ++a)
            #pragma unroll
            for (int c2 = 0; c2 < 3; ++c2)
                N[a * 3 + c2] = A[a * 3 + 0] * m[c2] + A[a * 3 + 1] * m[3 + c2] + A[a * 3 + 2] * m[6 + c2];
        #pragma unroll
        for (int i = 0; i < 9; ++i) A[i] = N[i];
    }
    {   // final fixed transform M_7 (constant affine)
        const float* d = cst + 210;
        float t0 = tr[0] + A[0] * d[9] + A[1] * d[10] + A[2] * d[11];
        float t1 = tr[1] + A[3] * d[9] + A[4] * d[10] + A[5] * d[11];
        float t2 = tr[2] + A[6] * d[9] + A[7] * d[10] + A[8] * d[11];
        tr[0] = t0; tr[1] = t1; tr[2] = t2;
        float N[9];
        #pragma unroll
        for (int a = 0; a < 3; ++a)
            #pragma unroll
            for (int c2 = 0; c2 < 3; ++c2)
                N[a * 3 + c2] = A[a * 3 + 0] * d[c2] + A[a * 3 + 1] * d[3 + c2] + A[a * 3 + 2] * d[6 + c2];
        #pragma unroll
        for (int i = 0; i < 9; ++i) A[i] = N[i];
    }

    // ---- XOR-swizzled wave-local transpose, then coalesced float4 stores ----
    // logical float4 slot s in [0,256): phys = s ^ ((s>>3)&7)
    //   write: s = 4l+k  -> (s>>3)&7 = (l>>1)&7  -> 8 lanes per bank-group (free)
    //   read:  s = l+64k -> (s>>3)&7 = (l>>3)&7  -> 8 lanes per bank-group (free)
    float4* wb4 = (float4*)wbuf;
    {
        const int x = (l >> 1) & 7;
        wb4[(4 * l + 0) ^ x] = make_float4(A[0], A[1], A[2], tr[0]);
        wb4[(4 * l + 1) ^ x] = make_float4(A[3], A[4], A[5], tr[1]);
        wb4[(4 * l + 2) ^ x] = make_float4(A[6], A[7], A[8], tr[2]);
        wb4[(4 * l + 3) ^ x] = make_float4(0.f, 0.f, 0.f, 1.f);
    }
    asm volatile("s_waitcnt lgkmcnt(0)" ::: "memory");
    {
        float4* o4 = (float4*)out + waveItem * 4;
        const int y = (l >> 3) & 7;
        #pragma unroll
        for (int k = 0; k < 4; ++k) {
            const int s = l + (k << 6);
            o4[s] = wb4[s ^ y];
        }
    }
}

extern "C" void kernel_launch(void* const* d_in, const int* in_sizes, int n_in,
                              void* d_out, int out_size, void* d_ws, size_t ws_size,
                              hipStream_t stream) {
    const float* jp = (const float*)d_in[0];   // joint_positions (B,7)
    const float* ft = (const float*)d_in[1];   // fixed_transforms (8,4,4)
    const float* ax = (const float*)d_in[2];   // joint_axes (7,3)
    float* out = (float*)d_out;
    float* cst = (float*)d_ws;                 // 222 floats of workspace
    const int B = in_sizes[0] / 7;             // 524288
    prep_kernel<<<dim3(1), dim3(64), 0, stream>>>(ft, ax, cst);
    fk_kernel<<<dim3(B / BLK), dim3(BLK), 0, stream>>>(jp, cst, out);
}